// Round 1
// baseline (584.908 us; speedup 1.0000x reference)
//
#include <hip/hip_runtime.h>

// Problem constants
#define B_    4
#define T_    4096
#define D_    1024
#define NH_   16
#define NS_   64
#define HD_   64
#define ALPHA_ 0.1f
#define M_    (B_*T_)        // 16384 rows
#define N_    (NH_*NS_)      // 1024 cols (head*slot)
#define NCH_  128            // time chunks for the suffix scan
#define CHUNK_ (T_/NCH_)     // 32

// ---------------------------------------------------------------------------
// Kernel 1: fold W_tok into prototypes:
//   P[n][m] = (1/8) * sum_{k<64} proto[s, h*64+k] * W_tok[h*64+k, m],  n = h*64+s
// so that score[b,t,n] = sum_m H[b,t,m] * P[n][m].
__global__ __launch_bounds__(256)
void k_protoproj(const float* __restrict__ proto,
                 const float* __restrict__ W,
                 float* __restrict__ P) {
    int n = blockIdx.x;              // 0..1023
    int h = n >> 6, s = n & 63;
    __shared__ float pl[64];
    int tid = threadIdx.x;
    if (tid < 64) pl[tid] = proto[s * D_ + h * 64 + tid];
    __syncthreads();
    #pragma unroll
    for (int j = 0; j < 4; ++j) {
        int m = j * 256 + tid;
        float acc = 0.f;
        #pragma unroll 16
        for (int k = 0; k < 64; ++k)
            acc += pl[k] * W[(h * 64 + k) * D_ + m];
        P[n * D_ + m] = 0.125f * acc;
    }
}

// ---------------------------------------------------------------------------
// Kernel 2: fp32 GEMM  C[m][n] = sum_k H[m][k] * P[n][k]
// 128x128 tile, BK=16, 256 threads, 8x8 micro-tile per thread.
#define BM 128
#define BN 128
#define BK 16
#define LDT 132   // padded LDS leading dim (breaks bank alignment)

__global__ __launch_bounds__(256)
void k_gemm_score(const float* __restrict__ A,   // H   [M_, D_]
                  const float* __restrict__ Bp,  // P   [N_, D_]
                  float* __restrict__ C) {       // out [M_, N_]
    __shared__ float As[BK][LDT];
    __shared__ float Bs[BK][LDT];
    int tid = threadIdx.x;
    int bn = blockIdx.x & 7;         // N_/BN = 8
    int bm = blockIdx.x >> 3;        // M_/BM = 128
    int m0 = bm * BM, n0 = bn * BN;
    int kg  = tid & 3;               // 4-float k group
    int row = tid >> 2;              // 0..63
    int ty = tid >> 4, tx = tid & 15;

    float acc[8][8] = {};

    for (int k0 = 0; k0 < D_; k0 += BK) {
        float4 a0 = *(const float4*)&A [(m0 + row)      * D_ + k0 + kg * 4];
        float4 a1 = *(const float4*)&A [(m0 + row + 64) * D_ + k0 + kg * 4];
        float4 b0 = *(const float4*)&Bp[(n0 + row)      * D_ + k0 + kg * 4];
        float4 b1 = *(const float4*)&Bp[(n0 + row + 64) * D_ + k0 + kg * 4];
        __syncthreads();   // previous tile's compute done before overwrite
        As[kg*4+0][row]    = a0.x; As[kg*4+1][row]    = a0.y;
        As[kg*4+2][row]    = a0.z; As[kg*4+3][row]    = a0.w;
        As[kg*4+0][row+64] = a1.x; As[kg*4+1][row+64] = a1.y;
        As[kg*4+2][row+64] = a1.z; As[kg*4+3][row+64] = a1.w;
        Bs[kg*4+0][row]    = b0.x; Bs[kg*4+1][row]    = b0.y;
        Bs[kg*4+2][row]    = b0.z; Bs[kg*4+3][row]    = b0.w;
        Bs[kg*4+0][row+64] = b1.x; Bs[kg*4+1][row+64] = b1.y;
        Bs[kg*4+2][row+64] = b1.z; Bs[kg*4+3][row+64] = b1.w;
        __syncthreads();
        #pragma unroll
        for (int kk = 0; kk < BK; ++kk) {
            float av[8], bv[8];
            *(float4*)&av[0] = *(const float4*)&As[kk][ty * 8];
            *(float4*)&av[4] = *(const float4*)&As[kk][ty * 8 + 4];
            *(float4*)&bv[0] = *(const float4*)&Bs[kk][tx * 8];
            *(float4*)&bv[4] = *(const float4*)&Bs[kk][tx * 8 + 4];
            #pragma unroll
            for (int i2 = 0; i2 < 8; ++i2)
                #pragma unroll
                for (int j2 = 0; j2 < 8; ++j2)
                    acc[i2][j2] += av[i2] * bv[j2];
        }
    }
    #pragma unroll
    for (int r = 0; r < 8; ++r) {
        float4 o;
        o.x = acc[r][0]; o.y = acc[r][1]; o.z = acc[r][2]; o.w = acc[r][3];
        *(float4*)&C[(m0 + ty * 8 + r) * N_ + n0 + tx * 8] = o;
        o.x = acc[r][4]; o.y = acc[r][5]; o.z = acc[r][6]; o.w = acc[r][7];
        *(float4*)&C[(m0 + ty * 8 + r) * N_ + n0 + tx * 8 + 4] = o;
    }
}

// ---------------------------------------------------------------------------
// Kernel 3: in-place softmax over the 64 slots of each (b,t,h) + per-chunk
// product of g = 1 - alpha*w. One wave = one (b,h,chunk); lane = slot.
__global__ __launch_bounds__(256)
void k_softmax_chunk(float* __restrict__ w, float* __restrict__ cp) {
    int gw   = blockIdx.x * 4 + (threadIdx.x >> 6);  // (b*16+h)*NCH_ + c
    int lane = threadIdx.x & 63;
    int c = gw & (NCH_ - 1);
    int h = (gw >> 7) & 15;      // NCH_=128 -> >>7
    int b = gw >> 11;            // /(128*16)
    float prod = 1.f;
    int t0 = c * CHUNK_;
    for (int t = t0; t < t0 + CHUNK_; ++t) {
        int idx = (b * T_ + t) * N_ + h * 64 + lane;
        float v = w[idx];
        float mx = v;
        #pragma unroll
        for (int off = 32; off; off >>= 1) mx = fmaxf(mx, __shfl_xor(mx, off));
        float e = __expf(v - mx);
        float sm = e;
        #pragma unroll
        for (int off = 32; off; off >>= 1) sm += __shfl_xor(sm, off);
        float wv = e / sm;
        w[idx] = wv;
        prod *= 1.f - ALPHA_ * wv;
    }
    cp[gw * 64 + lane] = prod;
}

// ---------------------------------------------------------------------------
// Kernel 4: cross-chunk EXCLUSIVE suffix product. One block per (b,h),
// thread = slot. csuf[b,h,c,s] = prod_{c'>c} cp[b,h,c',s]
__global__ __launch_bounds__(64)
void k_chunk_scan(const float* __restrict__ cp, float* __restrict__ csuf) {
    int bh = blockIdx.x;     // 0..63
    int s  = threadIdx.x;    // 0..63
    float suf = 1.f;
    for (int c = NCH_ - 1; c >= 0; --c) {
        int idx = (bh * NCH_ + c) * 64 + s;
        csuf[idx] = suf;
        suf *= cp[idx];
    }
}

// ---------------------------------------------------------------------------
// Kernel 5: finalize in place: w_eff[t] = alpha * w[t] * prod_{t'>t} g[t'].
// Walk each chunk backward starting from the cross-chunk suffix.
__global__ __launch_bounds__(256)
void k_weff(float* __restrict__ w, const float* __restrict__ csuf) {
    int gw   = blockIdx.x * 4 + (threadIdx.x >> 6);
    int lane = threadIdx.x & 63;
    int c = gw & (NCH_ - 1);
    int h = (gw >> 7) & 15;
    int b = gw >> 11;
    float suf = csuf[gw * 64 + lane];
    int t0 = c * CHUNK_;
    for (int t = t0 + CHUNK_ - 1; t >= t0; --t) {
        int idx = (b * T_ + t) * N_ + h * 64 + lane;
        float wv = w[idx];
        w[idx] = ALPHA_ * wv * suf;
        suf *= 1.f - ALPHA_ * wv;
    }
}

// ---------------------------------------------------------------------------
// Kernel 6: s[b,h,slot,:] = sum_t w_eff[b,t,h,slot] * H[b,t,h*64:...]
// block = (b,h,256-t chunk); LDS-tiled 64x64 outer product, atomicAdd out.
// out layout: [B, NS, NH, HD] flattened = [B, NS, D]
__global__ __launch_bounds__(256)
void k_out(const float* __restrict__ w,   // w_eff
           const float* __restrict__ H,
           float* __restrict__ out) {
    int bx = blockIdx.x;                  // 1024
    int cf = bx & 15, h = (bx >> 4) & 15, b = bx >> 8;
    __shared__ float ws_[32][64];
    __shared__ float hs_[32][64];
    int tid = threadIdx.x;
    int lr = tid >> 3;                    // 0..31
    int lc = (tid & 7) * 8;               // 0..56
    int i = tid >> 4, j = tid & 15;       // 16x16 thread grid -> 4s x 4d each
    float acc[4][4] = {};
    int t0 = cf * 256;
    for (int it = 0; it < 8; ++it) {
        int tb = t0 + it * 32;
        int base = (b * T_ + tb + lr) * N_ + h * 64 + lc;
        float4 wv0 = *(const float4*)&w[base];
        float4 wv1 = *(const float4*)&w[base + 4];
        float4 hv0 = *(const float4*)&H[base];
        float4 hv1 = *(const float4*)&H[base + 4];
        __syncthreads();
        *(float4*)&ws_[lr][lc]     = wv0;
        *(float4*)&ws_[lr][lc + 4] = wv1;
        *(float4*)&hs_[lr][lc]     = hv0;
        *(float4*)&hs_[lr][lc + 4] = hv1;
        __syncthreads();
        #pragma unroll
        for (int tt = 0; tt < 32; ++tt) {
            float4 a  = *(const float4*)&ws_[tt][i * 4];
            float4 bb = *(const float4*)&hs_[tt][j * 4];
            float av[4] = {a.x, a.y, a.z, a.w};
            float bv[4] = {bb.x, bb.y, bb.z, bb.w};
            #pragma unroll
            for (int ii = 0; ii < 4; ++ii)
                #pragma unroll
                for (int jj = 0; jj < 4; ++jj)
                    acc[ii][jj] += av[ii] * bv[jj];
        }
    }
    #pragma unroll
    for (int ii = 0; ii < 4; ++ii)
        #pragma unroll
        for (int jj = 0; jj < 4; ++jj)
            atomicAdd(&out[((b * NS_ + i * 4 + ii) * NH_ + h) * HD_ + j * 4 + jj],
                      acc[ii][jj]);
}

// ---------------------------------------------------------------------------
extern "C" void kernel_launch(void* const* d_in, const int* in_sizes, int n_in,
                              void* d_out, int out_size, void* d_ws, size_t ws_size,
                              hipStream_t stream) {
    const float* H     = (const float*)d_in[0];
    const float* proto = (const float*)d_in[1];
    const float* W     = (const float*)d_in[2];
    float* out = (float*)d_out;
    char*  ws  = (char*)d_ws;

    float* w    = (float*)ws;                                   // M_*N_ fp32 = 64 MB
    float* P    = (float*)(ws + (size_t)M_ * N_ * 4);           // N_*D_  = 4 MB
    float* cp   = (float*)(ws + (size_t)M_ * N_ * 4 + (size_t)N_ * D_ * 4); // 2 MB
    float* csuf = cp + (size_t)B_ * NH_ * NCH_ * 64;            // 2 MB

    hipMemsetAsync(d_out, 0, (size_t)out_size * sizeof(float), stream);

    k_protoproj   <<<N_,                 256, 0, stream>>>(proto, W, P);
    k_gemm_score  <<<(M_/BM)*(N_/BN),    256, 0, stream>>>(H, P, w);
    k_softmax_chunk<<<B_*NH_*NCH_/4,     256, 0, stream>>>(w, cp);
    k_chunk_scan  <<<B_*NH_,             64,  0, stream>>>(cp, csuf);
    k_weff        <<<B_*NH_*NCH_/4,      256, 0, stream>>>(w, csuf);
    k_out         <<<B_*NH_*16,          256, 0, stream>>>(w, H, out);
}

// Round 2
// 234.215 us; speedup vs baseline: 2.4973x; 2.4973x over previous
//
#include <hip/hip_runtime.h>

// Problem constants
#define B_    4
#define T_    4096
#define D_    1024
#define NH_   16
#define NS_   64
#define HD_   64
#define ALPHA_ 0.1f
#define M_    (B_*T_)        // 16384 rows
#define N_    (NH_*NS_)      // 1024 cols (head*slot)
#define NCH_  128            // time chunks for the suffix scan
#define CHUNK_ (T_/NCH_)     // 32

typedef __attribute__((ext_vector_type(8))) short short8v;
typedef __attribute__((ext_vector_type(4))) float f32x4;

__device__ inline unsigned short f2bf(float x) {
    unsigned u = __float_as_uint(x);
    unsigned r = u + 0x7FFF + ((u >> 16) & 1);   // RNE
    return (unsigned short)(r >> 16);
}

// ---------------------------------------------------------------------------
// Kernel 1: fold W_tok into prototypes, emit bf16:
//   P[n][m] = (1/8) * sum_{k<64} proto[s, h*64+k] * W_tok[h*64+k, m],  n = h*64+s
__global__ __launch_bounds__(256)
void k_protoproj(const float* __restrict__ proto,
                 const float* __restrict__ W,
                 unsigned short* __restrict__ Pb) {
    int n = blockIdx.x;              // 0..1023
    int h = n >> 6, s = n & 63;
    __shared__ float pl[64];
    int tid = threadIdx.x;
    if (tid < 64) pl[tid] = proto[s * D_ + h * 64 + tid];
    __syncthreads();
    #pragma unroll
    for (int j = 0; j < 4; ++j) {
        int m = j * 256 + tid;
        float acc = 0.f;
        #pragma unroll 16
        for (int k = 0; k < 64; ++k)
            acc += pl[k] * W[(h * 64 + k) * D_ + m];
        Pb[n * D_ + m] = f2bf(0.125f * acc);
    }
}

// ---------------------------------------------------------------------------
// Kernel 2: bf16 MFMA GEMM  C[m][n] = sum_k H[m][k] * P[n][k]   (fp32 out)
// 128x128 tile, BK=32, 256 threads = 4 waves (2x2 of 64x64), 16x16x32 MFMA.
// A (H, fp32) reg-staged with bf16 convert into padded LDS (LDA=40).
// B (Pb, bf16) staged via global_load_lds width 16 into linear LDS.
#define LDA_ 40

__global__ __launch_bounds__(256)
void k_gemm_mfma(const float* __restrict__ A,          // H  [M_, D_] fp32
                 const unsigned short* __restrict__ Bp,// Pb [N_, D_] bf16
                 float* __restrict__ C) {              // w  [M_, N_] fp32
    __shared__ short As[128 * LDA_];
    __shared__ short Bs[128 * 32];
    int tid = threadIdx.x;
    int bid = blockIdx.x;
    // XCD-bijective swizzle: 1024 blocks, 8 XCDs -> 128 per XCD
    int wgid = (bid & 7) * 128 + (bid >> 3);
    int bm = wgid >> 3, bn = wgid & 7;
    int m0 = bm * 128, n0 = bn * 128;
    int l = tid & 63, wv = tid >> 6;
    int wr = wv >> 1, wc = wv & 1;

    // A staging: 4 issues of 32 rows; thread -> row=arow+i*32, k-off=akof (4 floats)
    int arow = tid >> 3;          // 0..31
    int akof = (tid & 7) * 4;     // 0..28
    // B staging: 2 issues of 64 rows; thread -> row=brow(+64), k-off=bkof (8 bf16)
    int brow = tid >> 2;          // 0..63
    int bkof = (tid & 3) * 8;

    const float* Aptr = A + (size_t)(m0 + arow) * D_ + akof;
    const unsigned short* Bptr = Bp + (size_t)(n0 + brow) * D_ + bkof;

    f32x4 acc[4][4];
    #pragma unroll
    for (int i = 0; i < 4; ++i)
        #pragma unroll
        for (int j = 0; j < 4; ++j) acc[i][j] = (f32x4){0.f, 0.f, 0.f, 0.f};

    int lr = l & 15, lk = l >> 4;
    const short* afp = &As[(wr * 64 + lr) * LDA_ + lk * 8];
    const short* bfp = &Bs[(wc * 64 + lr) * 32 + lk * 8];

    for (int k0 = 0; k0 < D_; k0 += 32) {
        float4 a0 = *(const float4*)(Aptr + k0);
        float4 a1 = *(const float4*)(Aptr + (size_t)32 * D_ + k0);
        float4 a2 = *(const float4*)(Aptr + (size_t)64 * D_ + k0);
        float4 a3 = *(const float4*)(Aptr + (size_t)96 * D_ + k0);
        __syncthreads();   // previous tile's MFMA reads complete
        __builtin_amdgcn_global_load_lds(
            (const __attribute__((address_space(1))) void*)(Bptr + k0),
            (__attribute__((address_space(3))) void*)(&Bs[tid * 8]), 16, 0, 0);
        __builtin_amdgcn_global_load_lds(
            (const __attribute__((address_space(1))) void*)(Bptr + (size_t)64 * D_ + k0),
            (__attribute__((address_space(3))) void*)(&Bs[tid * 8 + 64 * 32]), 16, 0, 0);
        ushort4 p0 = {f2bf(a0.x), f2bf(a0.y), f2bf(a0.z), f2bf(a0.w)};
        ushort4 p1 = {f2bf(a1.x), f2bf(a1.y), f2bf(a1.z), f2bf(a1.w)};
        ushort4 p2 = {f2bf(a2.x), f2bf(a2.y), f2bf(a2.z), f2bf(a2.w)};
        ushort4 p3 = {f2bf(a3.x), f2bf(a3.y), f2bf(a3.z), f2bf(a3.w)};
        *(ushort4*)&As[(arow +  0) * LDA_ + akof] = p0;
        *(ushort4*)&As[(arow + 32) * LDA_ + akof] = p1;
        *(ushort4*)&As[(arow + 64) * LDA_ + akof] = p2;
        *(ushort4*)&As[(arow + 96) * LDA_ + akof] = p3;
        __syncthreads();   // staging visible (compiler adds vmcnt/lgkmcnt)
        short8v af[4], bf[4];
        #pragma unroll
        for (int m = 0; m < 4; ++m)
            af[m] = *(const short8v*)(afp + m * 16 * LDA_);
        #pragma unroll
        for (int n = 0; n < 4; ++n)
            bf[n] = *(const short8v*)(bfp + n * 16 * 32);
        #pragma unroll
        for (int m = 0; m < 4; ++m)
            #pragma unroll
            for (int n = 0; n < 4; ++n)
                acc[m][n] = __builtin_amdgcn_mfma_f32_16x16x32_bf16(
                    af[m], bf[n], acc[m][n], 0, 0, 0);
    }

    // C/D layout: col = lane&15, row = (lane>>4)*4 + j
    int crow = m0 + wr * 64 + lk * 4;
    int ccol = n0 + wc * 64 + lr;
    #pragma unroll
    for (int m = 0; m < 4; ++m)
        #pragma unroll
        for (int n = 0; n < 4; ++n)
            #pragma unroll
            for (int j = 0; j < 4; ++j)
                C[(size_t)(crow + m * 16 + j) * N_ + ccol + n * 16] = acc[m][n][j];
}

// ---------------------------------------------------------------------------
// Kernel 3: in-place softmax over the 64 slots of each (b,t,h) + per-chunk
// product of g = 1 - alpha*w. One wave = one (b,h,chunk); lane = slot.
__global__ __launch_bounds__(256)
void k_softmax_chunk(float* __restrict__ w, float* __restrict__ cp) {
    int gw   = blockIdx.x * 4 + (threadIdx.x >> 6);  // (b*16+h)*NCH_ + c
    int lane = threadIdx.x & 63;
    int c = gw & (NCH_ - 1);
    int h = (gw >> 7) & 15;
    int b = gw >> 11;
    float prod = 1.f;
    int t0 = c * CHUNK_;
    for (int t = t0; t < t0 + CHUNK_; ++t) {
        int idx = (b * T_ + t) * N_ + h * 64 + lane;
        float v = w[idx];
        float mx = v;
        #pragma unroll
        for (int off = 32; off; off >>= 1) mx = fmaxf(mx, __shfl_xor(mx, off));
        float e = __expf(v - mx);
        float sm = e;
        #pragma unroll
        for (int off = 32; off; off >>= 1) sm += __shfl_xor(sm, off);
        float wv = e / sm;
        w[idx] = wv;
        prod *= 1.f - ALPHA_ * wv;
    }
    cp[gw * 64 + lane] = prod;
}

// ---------------------------------------------------------------------------
// Kernel 4: cross-chunk EXCLUSIVE suffix product per (b,h); thread = slot.
__global__ __launch_bounds__(64)
void k_chunk_scan(const float* __restrict__ cp, float* __restrict__ csuf) {
    int bh = blockIdx.x;     // 0..63
    int s  = threadIdx.x;    // 0..63
    float suf = 1.f;
    for (int c = NCH_ - 1; c >= 0; --c) {
        int idx = (bh * NCH_ + c) * 64 + s;
        csuf[idx] = suf;
        suf *= cp[idx];
    }
}

// ---------------------------------------------------------------------------
// Kernel 5: finalize in place: w_eff[t] = alpha * w[t] * prod_{t'>t} g[t'].
__global__ __launch_bounds__(256)
void k_weff(float* __restrict__ w, const float* __restrict__ csuf) {
    int gw   = blockIdx.x * 4 + (threadIdx.x >> 6);
    int lane = threadIdx.x & 63;
    int c = gw & (NCH_ - 1);
    int h = (gw >> 7) & 15;
    int b = gw >> 11;
    float suf = csuf[gw * 64 + lane];
    int t0 = c * CHUNK_;
    for (int t = t0 + CHUNK_ - 1; t >= t0; --t) {
        int idx = (b * T_ + t) * N_ + h * 64 + lane;
        float wv = w[idx];
        w[idx] = ALPHA_ * wv * suf;
        suf *= 1.f - ALPHA_ * wv;
    }
}

// ---------------------------------------------------------------------------
// Kernel 6: s[b,h,slot,:] = sum_t w_eff[b,t,h,slot] * H[b,t,h*64:...]
__global__ __launch_bounds__(256)
void k_out(const float* __restrict__ w,   // w_eff
           const float* __restrict__ H,
           float* __restrict__ out) {
    int bx = blockIdx.x;                  // 1024
    int cf = bx & 15, h = (bx >> 4) & 15, b = bx >> 8;
    __shared__ float ws_[32][64];
    __shared__ float hs_[32][64];
    int tid = threadIdx.x;
    int lr = tid >> 3;                    // 0..31
    int lc = (tid & 7) * 8;               // 0..56
    int i = tid >> 4, j = tid & 15;       // 16x16 thread grid -> 4s x 4d each
    float acc[4][4] = {};
    int t0 = cf * 256;
    for (int it = 0; it < 8; ++it) {
        int tb = t0 + it * 32;
        int base = (b * T_ + tb + lr) * N_ + h * 64 + lc;
        float4 wv0 = *(const float4*)&w[base];
        float4 wv1 = *(const float4*)&w[base + 4];
        float4 hv0 = *(const float4*)&H[base];
        float4 hv1 = *(const float4*)&H[base + 4];
        __syncthreads();
        *(float4*)&ws_[lr][lc]     = wv0;
        *(float4*)&ws_[lr][lc + 4] = wv1;
        *(float4*)&hs_[lr][lc]     = hv0;
        *(float4*)&hs_[lr][lc + 4] = hv1;
        __syncthreads();
        #pragma unroll
        for (int tt = 0; tt < 32; ++tt) {
            float4 a  = *(const float4*)&ws_[tt][i * 4];
            float4 bb = *(const float4*)&hs_[tt][j * 4];
            float av[4] = {a.x, a.y, a.z, a.w};
            float bv[4] = {bb.x, bb.y, bb.z, bb.w};
            #pragma unroll
            for (int ii = 0; ii < 4; ++ii)
                #pragma unroll
                for (int jj = 0; jj < 4; ++jj)
                    acc[ii][jj] += av[ii] * bv[jj];
        }
    }
    #pragma unroll
    for (int ii = 0; ii < 4; ++ii)
        #pragma unroll
        for (int jj = 0; jj < 4; ++jj)
            atomicAdd(&out[((b * NS_ + i * 4 + ii) * NH_ + h) * HD_ + j * 4 + jj],
                      acc[ii][jj]);
}

// ---------------------------------------------------------------------------
extern "C" void kernel_launch(void* const* d_in, const int* in_sizes, int n_in,
                              void* d_out, int out_size, void* d_ws, size_t ws_size,
                              hipStream_t stream) {
    const float* H     = (const float*)d_in[0];
    const float* proto = (const float*)d_in[1];
    const float* W     = (const float*)d_in[2];
    float* out = (float*)d_out;
    char*  ws  = (char*)d_ws;

    float* w            = (float*)ws;                              // 64 MB
    unsigned short* Pb  = (unsigned short*)(ws + (size_t)M_ * N_ * 4);   // 2 MB
    float* cp   = (float*)(ws + (size_t)M_ * N_ * 4 + (size_t)N_ * D_ * 2); // 2 MB
    float* csuf = cp + (size_t)B_ * NH_ * NCH_ * 64;               // 2 MB

    hipMemsetAsync(d_out, 0, (size_t)out_size * sizeof(float), stream);

    k_protoproj    <<<N_,              256, 0, stream>>>(proto, W, Pb);
    k_gemm_mfma    <<<(M_/128)*(N_/128), 256, 0, stream>>>(H, Pb, w);
    k_softmax_chunk<<<B_*NH_*NCH_/4,   256, 0, stream>>>(w, cp);
    k_chunk_scan   <<<B_*NH_,          64,  0, stream>>>(cp, csuf);
    k_weff         <<<B_*NH_*NCH_/4,   256, 0, stream>>>(w, csuf);
    k_out          <<<B_*NH_*16,       256, 0, stream>>>(w, H, out);
}

// Round 3
// 190.089 us; speedup vs baseline: 3.0770x; 1.2321x over previous
//
#include <hip/hip_runtime.h>
#include <hip/hip_bf16.h>

// Problem constants
#define B_    4
#define T_    4096
#define D_    1024
#define NH_   16
#define NS_   64
#define HD_   64
#define ALPHA_ 0.1f
#define M_    (B_*T_)        // 16384 rows
#define N_    (NH_*NS_)      // 1024 cols (head*slot)
#define NCH_  128            // time chunks for the suffix scan
#define CHUNK_ (T_/NCH_)     // 32

typedef __attribute__((ext_vector_type(8))) short short8v;
typedef __attribute__((ext_vector_type(4))) float f32x4;

__device__ inline unsigned short f2bf(float x) {
    unsigned u = __float_as_uint(x);
    unsigned r = u + 0x7FFF + ((u >> 16) & 1);   // RNE
    return (unsigned short)(r >> 16);
}

// ---------------------------------------------------------------------------
// Kernel 1: fold W_tok into prototypes, emit bf16:
//   P[n][m] = (1/8) * sum_{k<64} proto[s, h*64+k] * W_tok[h*64+k, m],  n = h*64+s
__global__ __launch_bounds__(256)
void k_protoproj(const float* __restrict__ proto,
                 const float* __restrict__ W,
                 unsigned short* __restrict__ Pb) {
    int n = blockIdx.x;              // 0..1023
    int h = n >> 6, s = n & 63;
    __shared__ float pl[64];
    int tid = threadIdx.x;
    if (tid < 64) pl[tid] = proto[s * D_ + h * 64 + tid];
    __syncthreads();
    #pragma unroll
    for (int j = 0; j < 4; ++j) {
        int m = j * 256 + tid;
        float acc = 0.f;
        #pragma unroll 16
        for (int k = 0; k < 64; ++k)
            acc += pl[k] * W[(h * 64 + k) * D_ + m];
        Pb[n * D_ + m] = f2bf(0.125f * acc);
    }
}

// ---------------------------------------------------------------------------
// Kernel 2: bf16 MFMA GEMM + fused softmax + per-chunk g products.
//   scores C[m][n] = sum_k H[m][k] * P[n][k]; per (row, head): softmax over
//   64 slots; write softmaxed w (fp32) and cp[b,h,chunk,s] = prod g.
// 128x128 tile, BK=32, 4 waves (2x2 of 64x64), 16x16x32 MFMA.
// A (H fp32) reg-staged bf16 into padded LDS (LDA_=40 shorts = 80B rows).
// B (Pb bf16) via global_load_lds, XOR-swizzled global source (kgrp ^= row&3).
#define LDA_ 40

__global__ __launch_bounds__(256)
void k_gemm_sm(const float* __restrict__ A,          // H  [M_, D_] fp32
               const unsigned short* __restrict__ Bp,// Pb [N_, D_] bf16
               float* __restrict__ C,                // w  [M_, N_] fp32 (softmaxed)
               float* __restrict__ cp) {             // [B*NH, NCH, 64]
    __shared__ short As[128 * LDA_];
    __shared__ short Bs[128 * 32];
    int tid = threadIdx.x;
    int bid = blockIdx.x;
    // XCD-bijective swizzle: 1024 blocks, 8 XCDs -> 128 per XCD
    int wgid = (bid & 7) * 128 + (bid >> 3);
    int bm = wgid >> 3, bn = wgid & 7;
    int m0 = bm * 128, n0 = bn * 128;
    int l = tid & 63, wv = tid >> 6;
    int wr = wv >> 1, wc = wv & 1;

    // A staging: 4 issues of 32 rows; thread -> row=arow+i*32, k-off akof*4 floats
    int arow = tid >> 3;          // 0..31
    int akof = (tid & 7) * 4;     // shorts (0..28)
    // B staging: 2 issues of 64 rows; global k-group XOR-swizzled by row&3
    int brow = tid >> 2;          // 0..63
    int bkof = (((tid & 3) ^ ((tid >> 2) & 3))) * 8;  // shorts

    const float* Aptr = A + (size_t)(m0 + arow) * D_ + akof;
    const unsigned short* Bptr = Bp + (size_t)(n0 + brow) * D_ + bkof;

    f32x4 acc[4][4];
    #pragma unroll
    for (int i = 0; i < 4; ++i)
        #pragma unroll
        for (int j = 0; j < 4; ++j) acc[i][j] = (f32x4){0.f, 0.f, 0.f, 0.f};

    int lr = l & 15, lk = l >> 4;
    const short* afp = &As[(wr * 64 + lr) * LDA_ + lk * 8];
    // B read: physical kgrp = lk ^ (row&3); row = wc*64 + n*16 + lr, row&3 = lr&3
    const short* bfp = &Bs[(wc * 64 + lr) * 32 + (lk ^ (lr & 3)) * 8];

    for (int k0 = 0; k0 < D_; k0 += 32) {
        float4 a0 = *(const float4*)(Aptr + k0);
        float4 a1 = *(const float4*)(Aptr + (size_t)32 * D_ + k0);
        float4 a2 = *(const float4*)(Aptr + (size_t)64 * D_ + k0);
        float4 a3 = *(const float4*)(Aptr + (size_t)96 * D_ + k0);
        __syncthreads();   // previous tile's MFMA reads complete
        __builtin_amdgcn_global_load_lds(
            (const __attribute__((address_space(1))) void*)(Bptr + k0),
            (__attribute__((address_space(3))) void*)(&Bs[tid * 8]), 16, 0, 0);
        __builtin_amdgcn_global_load_lds(
            (const __attribute__((address_space(1))) void*)(Bptr + (size_t)64 * D_ + k0),
            (__attribute__((address_space(3))) void*)(&Bs[tid * 8 + 64 * 32]), 16, 0, 0);
        {
            __hip_bfloat162 q0 = __float22bfloat162_rn(make_float2(a0.x, a0.y));
            __hip_bfloat162 q1 = __float22bfloat162_rn(make_float2(a0.z, a0.w));
            __hip_bfloat162 q2 = __float22bfloat162_rn(make_float2(a1.x, a1.y));
            __hip_bfloat162 q3 = __float22bfloat162_rn(make_float2(a1.z, a1.w));
            __hip_bfloat162 q4 = __float22bfloat162_rn(make_float2(a2.x, a2.y));
            __hip_bfloat162 q5 = __float22bfloat162_rn(make_float2(a2.z, a2.w));
            __hip_bfloat162 q6 = __float22bfloat162_rn(make_float2(a3.x, a3.y));
            __hip_bfloat162 q7 = __float22bfloat162_rn(make_float2(a3.z, a3.w));
            uint2 u0 = {*(unsigned*)&q0, *(unsigned*)&q1};
            uint2 u1 = {*(unsigned*)&q2, *(unsigned*)&q3};
            uint2 u2 = {*(unsigned*)&q4, *(unsigned*)&q5};
            uint2 u3 = {*(unsigned*)&q6, *(unsigned*)&q7};
            *(uint2*)&As[(arow +  0) * LDA_ + akof] = u0;
            *(uint2*)&As[(arow + 32) * LDA_ + akof] = u1;
            *(uint2*)&As[(arow + 64) * LDA_ + akof] = u2;
            *(uint2*)&As[(arow + 96) * LDA_ + akof] = u3;
        }
        __syncthreads();   // staging visible
        short8v af[4], bf[4];
        #pragma unroll
        for (int m = 0; m < 4; ++m)
            af[m] = *(const short8v*)(afp + m * 16 * LDA_);
        #pragma unroll
        for (int n = 0; n < 4; ++n)
            bf[n] = *(const short8v*)(bfp + n * 16 * 32);
        #pragma unroll
        for (int m = 0; m < 4; ++m)
            #pragma unroll
            for (int n = 0; n < 4; ++n)
                acc[m][n] = __builtin_amdgcn_mfma_f32_16x16x32_bf16(
                    af[m], bf[n], acc[m][n], 0, 0, 0);
    }

    // ---- fused epilogue: softmax over slots, g-products per chunk ----
    // acc layout: row = m0 + wr*64 + m*16 + lk*4 + j ; col = n0 + wc*64 + n*16 + lr
    float pch0[4] = {1.f, 1.f, 1.f, 1.f};   // chunk 2wr   (m = 0,1)
    float pch1[4] = {1.f, 1.f, 1.f, 1.f};   // chunk 2wr+1 (m = 2,3)
    #pragma unroll
    for (int m = 0; m < 4; ++m) {
        #pragma unroll
        for (int j = 0; j < 4; ++j) {
            float v0 = acc[m][0][j], v1 = acc[m][1][j];
            float v2 = acc[m][2][j], v3 = acc[m][3][j];
            float mx = fmaxf(fmaxf(v0, v1), fmaxf(v2, v3));
            #pragma unroll
            for (int off = 1; off <= 8; off <<= 1)
                mx = fmaxf(mx, __shfl_xor(mx, off));
            float e0 = __expf(v0 - mx), e1 = __expf(v1 - mx);
            float e2 = __expf(v2 - mx), e3 = __expf(v3 - mx);
            float sm = e0 + e1 + e2 + e3;
            #pragma unroll
            for (int off = 1; off <= 8; off <<= 1)
                sm += __shfl_xor(sm, off);
            float inv = 1.f / sm;
            float w0 = e0 * inv, w1 = e1 * inv, w2 = e2 * inv, w3 = e3 * inv;
            acc[m][0][j] = w0; acc[m][1][j] = w1;
            acc[m][2][j] = w2; acc[m][3][j] = w3;
            float* pc = (m < 2) ? pch0 : pch1;
            pc[0] *= 1.f - ALPHA_ * w0;
            pc[1] *= 1.f - ALPHA_ * w1;
            pc[2] *= 1.f - ALPHA_ * w2;
            pc[3] *= 1.f - ALPHA_ * w3;
        }
    }
    // combine the 4 lk groups (rows interleave across lanes 16 apart)
    #pragma unroll
    for (int n = 0; n < 4; ++n) {
        pch0[n] *= __shfl_xor(pch0[n], 16);
        pch0[n] *= __shfl_xor(pch0[n], 32);
        pch1[n] *= __shfl_xor(pch1[n], 16);
        pch1[n] *= __shfl_xor(pch1[n], 32);
    }
    {
        int b = m0 >> 12;                       // T_ = 4096 rows per batch
        int h = bn * 2 + wc;
        int cl = ((m0 & (T_ - 1)) >> 5) + 2 * wr;
        int gwb = (b * NH_ + h) * NCH_;
        if (lk == 0) {
            #pragma unroll
            for (int n = 0; n < 4; ++n) {
                cp[(gwb + cl)     * 64 + n * 16 + lr] = pch0[n];
                cp[(gwb + cl + 1) * 64 + n * 16 + lr] = pch1[n];
            }
        }
    }
    // store softmaxed w
    int crow = m0 + wr * 64 + lk * 4;
    int ccol = n0 + wc * 64 + lr;
    #pragma unroll
    for (int m = 0; m < 4; ++m)
        #pragma unroll
        for (int n = 0; n < 4; ++n)
            #pragma unroll
            for (int j = 0; j < 4; ++j)
                C[(size_t)(crow + m * 16 + j) * N_ + ccol + n * 16] = acc[m][n][j];
}

// ---------------------------------------------------------------------------
// Kernel 3: cross-chunk EXCLUSIVE suffix product per (b,h); thread = slot.
__global__ __launch_bounds__(64)
void k_chunk_scan(const float* __restrict__ cp, float* __restrict__ csuf) {
    int bh = blockIdx.x;     // 0..63
    int s  = threadIdx.x;    // 0..63
    float suf = 1.f;
    for (int c = NCH_ - 1; c >= 0; --c) {
        int idx = (bh * NCH_ + c) * 64 + s;
        csuf[idx] = suf;
        suf *= cp[idx];
    }
}

// ---------------------------------------------------------------------------
// Kernel 4: fused weff + output accumulation.
//   Per LDS tile (32 t x 64 s): 3-phase parallel suffix walk turns softmaxed w
//   into w_eff in-place, then 64x64 outer-product accumulate, atomicAdd to out.
// out layout: [B, NS, NH, HD]
__global__ __launch_bounds__(256)
void k_out_fused(const float* __restrict__ w,     // softmaxed
                 const float* __restrict__ H,
                 const float* __restrict__ csuf,
                 float* __restrict__ out) {
    int bx = blockIdx.x;                  // 1024
    int cf = bx & 15, h = (bx >> 4) & 15, b = bx >> 8;
    __shared__ float ws_[32][64];
    __shared__ float hs_[32][64];
    __shared__ float ppl[4][64];
    int tid = threadIdx.x;
    int lr = tid >> 3;                    // 0..31  (tile load row)
    int lc = (tid & 7) * 8;               // 0..56  (tile load col)
    int i = tid >> 4, j = tid & 15;       // outer-product thread grid
    int s = tid & 63, q = tid >> 6;       // walk: slot s, wave-uniform quarter q
    float acc[4][4] = {};
    int t0 = cf * 256;
    int gwb = (b * NH_ + h) * NCH_ + cf * 8;
    for (int it = 0; it < 8; ++it) {
        int tb = t0 + it * 32;
        int base = (b * T_ + tb + lr) * N_ + h * 64 + lc;
        float4 wv0 = *(const float4*)&w[base];
        float4 wv1 = *(const float4*)&w[base + 4];
        float4 hv0 = *(const float4*)&H[base];
        float4 hv1 = *(const float4*)&H[base + 4];
        float su = csuf[(gwb + it) * 64 + s];
        __syncthreads();                  // prior iteration's LDS reads done
        *(float4*)&ws_[lr][lc]     = wv0;
        *(float4*)&ws_[lr][lc + 4] = wv1;
        *(float4*)&hs_[lr][lc]     = hv0;
        *(float4*)&hs_[lr][lc + 4] = hv1;
        __syncthreads();                  // tiles visible
        // phase 1: per-quarter partial products of g = 1 - alpha*w
        float pp = 1.f;
        #pragma unroll
        for (int r = 0; r < 8; ++r) pp *= 1.f - ALPHA_ * ws_[q * 8 + r][s];
        ppl[q][s] = pp;
        __syncthreads();                  // ppl visible
        // phase 2: suffix start for this quarter, then backward walk
        float suf = su;
        if (q <= 2) suf *= ppl[3][s];
        if (q <= 1) suf *= ppl[2][s];
        if (q == 0) suf *= ppl[1][s];
        #pragma unroll
        for (int r = 7; r >= 0; --r) {
            float wv = ws_[q * 8 + r][s];
            ws_[q * 8 + r][s] = ALPHA_ * wv * suf;
            suf *= 1.f - ALPHA_ * wv;
        }
        __syncthreads();                  // w_eff visible
        // outer product: acc[slot-quad][d-quad] over 32 t
        #pragma unroll 8
        for (int tt = 0; tt < 32; ++tt) {
            float4 a  = *(const float4*)&ws_[tt][i * 4];
            float4 bb = *(const float4*)&hs_[tt][j * 4];
            float av[4] = {a.x, a.y, a.z, a.w};
            float bv[4] = {bb.x, bb.y, bb.z, bb.w};
            #pragma unroll
            for (int ii = 0; ii < 4; ++ii)
                #pragma unroll
                for (int jj = 0; jj < 4; ++jj)
                    acc[ii][jj] += av[ii] * bv[jj];
        }
    }
    #pragma unroll
    for (int ii = 0; ii < 4; ++ii)
        #pragma unroll
        for (int jj = 0; jj < 4; ++jj)
            atomicAdd(&out[((b * NS_ + i * 4 + ii) * NH_ + h) * HD_ + j * 4 + jj],
                      acc[ii][jj]);
}

// ---------------------------------------------------------------------------
extern "C" void kernel_launch(void* const* d_in, const int* in_sizes, int n_in,
                              void* d_out, int out_size, void* d_ws, size_t ws_size,
                              hipStream_t stream) {
    const float* H     = (const float*)d_in[0];
    const float* proto = (const float*)d_in[1];
    const float* W     = (const float*)d_in[2];
    float* out = (float*)d_out;
    char*  ws  = (char*)d_ws;

    float* w            = (float*)ws;                                    // 64 MB
    unsigned short* Pb  = (unsigned short*)(ws + (size_t)M_ * N_ * 4);   // 2 MB
    float* cp   = (float*)(ws + (size_t)M_ * N_ * 4 + (size_t)N_ * D_ * 2); // 2 MB
    float* csuf = cp + (size_t)B_ * NH_ * NCH_ * 64;                     // 2 MB

    hipMemsetAsync(d_out, 0, (size_t)out_size * sizeof(float), stream);

    k_protoproj <<<N_,                256, 0, stream>>>(proto, W, Pb);
    k_gemm_sm   <<<(M_/128)*(N_/128), 256, 0, stream>>>(H, Pb, w, cp);
    k_chunk_scan<<<B_*NH_,            64,  0, stream>>>(cp, csuf);
    k_out_fused <<<B_*NH_*16,         256, 0, stream>>>(w, H, csuf, out);
}